// Round 1
// baseline (1914.587 us; speedup 1.0000x reference)
//
#include <hip/hip_runtime.h>

// LinearAttentionBlock: y = x2 + relu(x2@W1'+b1)@W2'+b2, x2 = x + (Q@(K'V))@Wp'+bp
// Reassociated linear attention: (Q@K')@V == Q@(K'@V), K'V is 128x128.
// All fp32 this round (correctness baseline); MFMA/bf16 in later rounds.

#define MROWS 8192
#define DMODEL 1024
#define DK 128
#define DFF 4096

// ---------------------------------------------------------------------------
// Generic tiled fp32 GEMM: C[M,N] = act(A[M,K] @ W[N,K]^T + bias) (+ resid)
// BM=BN=64, BK=16, 256 threads, 4x4 microtile per thread.
// M%64==0, N%64==0, K%16==0 (true for all our shapes).
// ---------------------------------------------------------------------------
template<bool RELU, bool RESID, bool BIAS>
__global__ __launch_bounds__(256) void gemm_atb(
    const float* __restrict__ A, const float* __restrict__ W,
    const float* __restrict__ bias, const float* __restrict__ resid,
    float* __restrict__ C, int M, int N, int K)
{
    constexpr int BM = 64, BN = 64, BK = 16;
    __shared__ float As[BK][BM + 4];   // row stride 68 floats = 272B (16B aligned)
    __shared__ float Ws[BK][BN + 4];

    const int row0 = blockIdx.y * BM;
    const int col0 = blockIdx.x * BN;
    const int tid  = threadIdx.x;
    const int tx   = tid & 15;         // 16 cols of threads
    const int ty   = tid >> 4;         // 16 rows of threads
    const int lr   = tid >> 2;         // loader row 0..63
    const int lc   = (tid & 3) << 2;   // loader col {0,4,8,12}

    float acc[4][4] = {};

    for (int k0 = 0; k0 < K; k0 += BK) {
        const float4 a4 = *reinterpret_cast<const float4*>(
            &A[(size_t)(row0 + lr) * K + k0 + lc]);
        const float4 w4 = *reinterpret_cast<const float4*>(
            &W[(size_t)(col0 + lr) * K + k0 + lc]);
        As[lc + 0][lr] = a4.x; As[lc + 1][lr] = a4.y;
        As[lc + 2][lr] = a4.z; As[lc + 3][lr] = a4.w;
        Ws[lc + 0][lr] = w4.x; Ws[lc + 1][lr] = w4.y;
        Ws[lc + 2][lr] = w4.z; Ws[lc + 3][lr] = w4.w;
        __syncthreads();
        #pragma unroll
        for (int k = 0; k < BK; k++) {
            const float4 ra4 = *reinterpret_cast<const float4*>(&As[k][ty << 2]);
            const float4 rb4 = *reinterpret_cast<const float4*>(&Ws[k][tx << 2]);
            const float ra[4] = { ra4.x, ra4.y, ra4.z, ra4.w };
            const float rb[4] = { rb4.x, rb4.y, rb4.z, rb4.w };
            #pragma unroll
            for (int i = 0; i < 4; i++)
                #pragma unroll
                for (int j = 0; j < 4; j++)
                    acc[i][j] = fmaf(ra[i], rb[j], acc[i][j]);
        }
        __syncthreads();
    }

    // epilogue
    #pragma unroll
    for (int i = 0; i < 4; i++) {
        const size_t r = row0 + (ty << 2) + i;
        const int    c = col0 + (tx << 2);
        float v[4];
        #pragma unroll
        for (int j = 0; j < 4; j++) v[j] = acc[i][j];
        if constexpr (BIAS) {
            const float4 b4 = *reinterpret_cast<const float4*>(&bias[c]);
            v[0] += b4.x; v[1] += b4.y; v[2] += b4.z; v[3] += b4.w;
        }
        if constexpr (RESID) {
            const float4 r4 = *reinterpret_cast<const float4*>(&resid[r * N + c]);
            v[0] += r4.x; v[1] += r4.y; v[2] += r4.z; v[3] += r4.w;
        }
        if constexpr (RELU) {
            #pragma unroll
            for (int j = 0; j < 4; j++) v[j] = fmaxf(v[j], 0.0f);
        }
        *reinterpret_cast<float4*>(&C[r * N + c]) =
            make_float4(v[0], v[1], v[2], v[3]);
    }
}

// ---------------------------------------------------------------------------
// K^T @ V partial: 64 blocks, each reduces 128 rows into a [128][128] partial.
// Deterministic (no atomics).
// ---------------------------------------------------------------------------
__global__ __launch_bounds__(256) void ktv_partial(
    const float* __restrict__ Km, const float* __restrict__ Vm,
    float* __restrict__ part)
{
    __shared__ float ks[32][DK];
    __shared__ float vs[32][DK];
    const int tid = threadIdx.x;
    const int ti  = tid >> 4;   // 0..15 -> rows of KtV (i), 8 each
    const int tj  = tid & 15;   // 0..15 -> cols of KtV (j), 8 each
    float acc[8][8] = {};
    const size_t base = (size_t)blockIdx.x * 128;

    for (int n0 = 0; n0 < 128; n0 += 32) {
        for (int t = tid; t < 1024; t += 256) {       // 1024 float4s = 32x128
            const int r  = t >> 5;
            const int cc = (t & 31) << 2;
            *reinterpret_cast<float4*>(&ks[r][cc]) =
                *reinterpret_cast<const float4*>(&Km[(base + n0 + r) * DK + cc]);
            *reinterpret_cast<float4*>(&vs[r][cc]) =
                *reinterpret_cast<const float4*>(&Vm[(base + n0 + r) * DK + cc]);
        }
        __syncthreads();
        for (int n = 0; n < 32; n++) {
            float kk[8], vv[8];
            #pragma unroll
            for (int i = 0; i < 8; i++) kk[i] = ks[n][(ti << 3) + i];
            #pragma unroll
            for (int j = 0; j < 8; j++) vv[j] = vs[n][(tj << 3) + j];
            #pragma unroll
            for (int i = 0; i < 8; i++)
                #pragma unroll
                for (int j = 0; j < 8; j++)
                    acc[i][j] = fmaf(kk[i], vv[j], acc[i][j]);
        }
        __syncthreads();
    }

    float* dst = &part[(size_t)blockIdx.x * (DK * DK)];
    #pragma unroll
    for (int i = 0; i < 8; i++) {
        const int ig = (ti << 3) + i;
        *reinterpret_cast<float4*>(&dst[ig * DK + (tj << 3)]) =
            make_float4(acc[i][0], acc[i][1], acc[i][2], acc[i][3]);
        *reinterpret_cast<float4*>(&dst[ig * DK + (tj << 3) + 4]) =
            make_float4(acc[i][4], acc[i][5], acc[i][6], acc[i][7]);
    }
}

// Reduce 64 partials; write TRANSPOSED so gemm_atb can consume it as W[N,K].
__global__ __launch_bounds__(256) void ktv_reduce(
    const float* __restrict__ part, float* __restrict__ ktvT)
{
    const int t = blockIdx.x * 256 + threadIdx.x;   // 0..16383
    const int i = t >> 7;
    const int j = t & 127;
    float s = 0.0f;
    for (int b = 0; b < 64; b++) s += part[(size_t)b * (DK * DK) + t];
    ktvT[j * DK + i] = s;   // ktvT[j][i] = KtV[i][j]
}

// ---------------------------------------------------------------------------
extern "C" void kernel_launch(void* const* d_in, const int* in_sizes, int n_in,
                              void* d_out, int out_size, void* d_ws, size_t ws_size,
                              hipStream_t stream) {
    const float* x  = (const float*)d_in[0];
    const float* Wq = (const float*)d_in[1];
    const float* bq = (const float*)d_in[2];
    const float* Wk = (const float*)d_in[3];
    const float* bk = (const float*)d_in[4];
    const float* Wv = (const float*)d_in[5];
    const float* bv = (const float*)d_in[6];
    const float* Wp = (const float*)d_in[7];
    const float* bp = (const float*)d_in[8];
    const float* W1 = (const float*)d_in[9];
    const float* b1 = (const float*)d_in[10];
    const float* W2 = (const float*)d_in[11];
    const float* b2 = (const float*)d_in[12];
    float* out = (float*)d_out;

    char* ws = (char*)d_ws;
    float* Q    = (float*)(ws);                         //  4 MB
    float* Kb   = (float*)(ws + ( 4ull << 20));         //  4 MB
    float* Vb   = (float*)(ws + ( 8ull << 20));         //  4 MB
    float* Ctx  = (float*)(ws + (12ull << 20));         //  4 MB
    float* KtvT = (float*)(ws + (16ull << 20));         // 64 KB
    float* Part = (float*)(ws + (17ull << 20));         //  4 MB (64 x 64KB)
    float* H    = (float*)(ws + (22ull << 20));         // 128 MB -> ends at 150 MB

    const dim3 blk(256);

    // Q/K/V projections: [8192,1024] @ [1024,128]^T + b
    gemm_atb<false,false,true><<<dim3(2,128), blk, 0, stream>>>(x, Wq, bq, nullptr, Q,  MROWS, DK, DMODEL);
    gemm_atb<false,false,true><<<dim3(2,128), blk, 0, stream>>>(x, Wk, bk, nullptr, Kb, MROWS, DK, DMODEL);
    gemm_atb<false,false,true><<<dim3(2,128), blk, 0, stream>>>(x, Wv, bv, nullptr, Vb, MROWS, DK, DMODEL);

    // KtV = K^T @ V  (deterministic 2-stage reduction), stored transposed
    ktv_partial<<<dim3(64), blk, 0, stream>>>(Kb, Vb, Part);
    ktv_reduce <<<dim3(64), blk, 0, stream>>>(Part, KtvT);

    // context = Q @ KtV   (uses KtV^T as the [N,K] weight)
    gemm_atb<false,false,false><<<dim3(2,128), blk, 0, stream>>>(Q, KtvT, nullptr, nullptr, Ctx, MROWS, DK, DK);

    // x2 = x + context @ Wp^T + bp   -> stored in d_out
    gemm_atb<false,true,true><<<dim3(16,128), blk, 0, stream>>>(Ctx, Wp, bp, x, out, MROWS, DMODEL, DK);

    // h = relu(x2 @ W1^T + b1)
    gemm_atb<true,false,true><<<dim3(64,128), blk, 0, stream>>>(out, W1, b1, nullptr, H, MROWS, DFF, DMODEL);

    // y = x2 + h @ W2^T + b2   (in-place residual read from d_out is same-thread)
    gemm_atb<false,true,true><<<dim3(16,128), blk, 0, stream>>>(H, W2, b2, out, out, MROWS, DMODEL, DFF);
}

// Round 2
// 308.628 us; speedup vs baseline: 6.2035x; 6.2035x over previous
//
#include <hip/hip_runtime.h>

// LinearAttentionBlock, bf16 MFMA version.
// y = x2 + relu(x2@W1'+b1)@W2'+b2,  x2 = x + (Q@(K'V))@Wp'+bp
// Linear attention reassociated: (Q@K')@V == Q@(K'@V); K'V is 128x128.
// All GEMMs: m97 structure (128x128 tile, BK=32, mfma_f32_16x16x32_bf16,
// global_load_lds width=16, two-barrier loop).

#define MROWS 8192
#define DMODEL 1024
#define DK 128
#define DFF 4096

typedef __attribute__((ext_vector_type(8))) __bf16 bf16x8;
typedef __attribute__((ext_vector_type(4))) float f32x4;

// ---------------------------------------------------------------------------
// cast fp32 -> bf16, 8 elements/thread, grid-stride
// ---------------------------------------------------------------------------
__global__ __launch_bounds__(256) void cast_f32_bf16(
    const float* __restrict__ src, __bf16* __restrict__ dst, int n8)
{
    for (int i = blockIdx.x * blockDim.x + threadIdx.x; i < n8;
         i += gridDim.x * blockDim.x) {
        const float4 a = reinterpret_cast<const float4*>(src)[2 * i];
        const float4 b = reinterpret_cast<const float4*>(src)[2 * i + 1];
        bf16x8 o;
        o[0] = (__bf16)a.x; o[1] = (__bf16)a.y; o[2] = (__bf16)a.z; o[3] = (__bf16)a.w;
        o[4] = (__bf16)b.x; o[5] = (__bf16)b.y; o[6] = (__bf16)b.z; o[7] = (__bf16)b.w;
        reinterpret_cast<bf16x8*>(dst)[i] = o;
    }
}

__global__ void pack_bias3(const float* __restrict__ a, const float* __restrict__ b,
                           const float* __restrict__ c, float* __restrict__ o)
{
    const int t = threadIdx.x;  // 128 threads
    o[t] = a[t]; o[128 + t] = b[t]; o[256 + t] = c[t];
}

// ---------------------------------------------------------------------------
// bf16 MFMA GEMM: C[M,N] = act(A[M,K(lda)] @ W[N,K]^T + bias) (+ resid)
// grid = (N/128, M/128), block = 256 (4 waves, 2x2, each 64x64 out).
// M%128==0, N%128==0, K%32==0. W dense [N][K]. resid/C use ldc.
// ---------------------------------------------------------------------------
template<bool RELU, bool RESID, bool BIAS, bool OUTBF>
__global__ __launch_bounds__(256) void gemm_bf16(
    const __bf16* __restrict__ A, int lda,
    const __bf16* __restrict__ W,
    const float* __restrict__ bias,
    const float* __restrict__ resid,
    void* __restrict__ Cout, int ldc, int K)
{
    constexpr int BM = 128, BN = 128, BK = 32;
    __shared__ __bf16 As[BM * BK];
    __shared__ __bf16 Bs[BN * BK];

    const int tid  = threadIdx.x;
    const int lane = tid & 63;
    const int w    = tid >> 6;        // wave 0..3
    const int wm   = w >> 1;          // wave row 0..1
    const int wn   = w & 1;           // wave col 0..1
    const int fr   = lane & 15;       // fragment row/col
    const int fq   = lane >> 4;       // k-group / row-quad

    const long row0 = (long)blockIdx.y * BM;
    const long col0 = (long)blockIdx.x * BN;

    // staging: per-lane source position within a 64-row stripe
    const int sr = (w << 4) + (lane >> 2);   // 0..63
    const int sc = (lane & 3) << 3;          // 0,8,16,24

    const __bf16* gA0 = A + (row0 + sr) * (long)lda + sc;
    const __bf16* gA1 = A + (row0 + 64 + sr) * (long)lda + sc;
    const __bf16* gW0 = W + (col0 + sr) * (long)K + sc;
    const __bf16* gW1 = W + (col0 + 64 + sr) * (long)K + sc;

    __bf16* lA0 = &As[(w << 4) * BK];
    __bf16* lA1 = &As[((w << 4) + 64) * BK];
    __bf16* lB0 = &Bs[(w << 4) * BK];
    __bf16* lB1 = &Bs[((w << 4) + 64) * BK];

    f32x4 acc[4][4] = {};

    for (int k0 = 0; k0 < K; k0 += BK) {
        __builtin_amdgcn_global_load_lds(
            (const __attribute__((address_space(1))) void*)(gA0 + k0),
            (__attribute__((address_space(3))) void*)lA0, 16, 0, 0);
        __builtin_amdgcn_global_load_lds(
            (const __attribute__((address_space(1))) void*)(gA1 + k0),
            (__attribute__((address_space(3))) void*)lA1, 16, 0, 0);
        __builtin_amdgcn_global_load_lds(
            (const __attribute__((address_space(1))) void*)(gW0 + k0),
            (__attribute__((address_space(3))) void*)lB0, 16, 0, 0);
        __builtin_amdgcn_global_load_lds(
            (const __attribute__((address_space(1))) void*)(gW1 + k0),
            (__attribute__((address_space(3))) void*)lB1, 16, 0, 0);
        __syncthreads();

        bf16x8 af[4], bfr[4];
        #pragma unroll
        for (int m = 0; m < 4; m++)
            af[m] = *reinterpret_cast<const bf16x8*>(
                &As[(wm * 64 + m * 16 + fr) * BK + fq * 8]);
        #pragma unroll
        for (int n = 0; n < 4; n++)
            bfr[n] = *reinterpret_cast<const bf16x8*>(
                &Bs[(wn * 64 + n * 16 + fr) * BK + fq * 8]);

        #pragma unroll
        for (int m = 0; m < 4; m++)
            #pragma unroll
            for (int n = 0; n < 4; n++)
                acc[m][n] = __builtin_amdgcn_mfma_f32_16x16x32_bf16(
                    af[m], bfr[n], acc[m][n], 0, 0, 0);
        __syncthreads();
    }

    // epilogue: C/D layout col = lane&15, row = (lane>>4)*4 + reg
    #pragma unroll
    for (int n = 0; n < 4; n++) {
        const long c = col0 + wn * 64 + n * 16 + fr;
        float bc = 0.0f;
        if constexpr (BIAS) bc = bias[c];
        #pragma unroll
        for (int m = 0; m < 4; m++) {
            #pragma unroll
            for (int j = 0; j < 4; j++) {
                const long r = row0 + wm * 64 + m * 16 + fq * 4 + j;
                float v = acc[m][n][j];
                if constexpr (BIAS)  v += bc;
                if constexpr (RESID) v += resid[r * ldc + c];
                if constexpr (RELU)  v = fmaxf(v, 0.0f);
                if constexpr (OUTBF) ((__bf16*)Cout)[r * ldc + c] = (__bf16)v;
                else                 ((float*)Cout)[r * ldc + c] = v;
            }
        }
    }
}

// ---------------------------------------------------------------------------
// K^T @ V partials from bf16 K,V (packed, leading dim ld).
// 64 blocks x 128 rows each -> part[b][128][128] fp32. Deterministic.
// ---------------------------------------------------------------------------
__global__ __launch_bounds__(256) void ktv_partial(
    const __bf16* __restrict__ Kp, const __bf16* __restrict__ Vp,
    int ld, float* __restrict__ part)
{
    __shared__ float ks[32][DK];
    __shared__ float vs[32][DK];
    const int tid = threadIdx.x;
    const int ti  = tid >> 4;
    const int tj  = tid & 15;
    float acc[8][8] = {};
    const long base = (long)blockIdx.x * 128;

    for (int n0 = 0; n0 < 128; n0 += 32) {
        for (int t = tid; t < 512; t += 256) {      // 32 rows x 16 chunks of 8
            const int r  = t >> 4;
            const int cc = (t & 15) << 3;
            const bf16x8 k8 = *reinterpret_cast<const bf16x8*>(
                &Kp[(base + n0 + r) * (long)ld + cc]);
            const bf16x8 v8 = *reinterpret_cast<const bf16x8*>(
                &Vp[(base + n0 + r) * (long)ld + cc]);
            #pragma unroll
            for (int u = 0; u < 8; u++) {
                ks[r][cc + u] = (float)k8[u];
                vs[r][cc + u] = (float)v8[u];
            }
        }
        __syncthreads();
        for (int n = 0; n < 32; n++) {
            float kk[8], vv[8];
            #pragma unroll
            for (int i = 0; i < 8; i++) kk[i] = ks[n][(ti << 3) + i];
            #pragma unroll
            for (int j = 0; j < 8; j++) vv[j] = vs[n][(tj << 3) + j];
            #pragma unroll
            for (int i = 0; i < 8; i++)
                #pragma unroll
                for (int j = 0; j < 8; j++)
                    acc[i][j] = fmaf(kk[i], vv[j], acc[i][j]);
        }
        __syncthreads();
    }

    float* dst = &part[(long)blockIdx.x * (DK * DK)];
    #pragma unroll
    for (int i = 0; i < 8; i++) {
        const int ig = (ti << 3) + i;
        *reinterpret_cast<float4*>(&dst[ig * DK + (tj << 3)]) =
            make_float4(acc[i][0], acc[i][1], acc[i][2], acc[i][3]);
        *reinterpret_cast<float4*>(&dst[ig * DK + (tj << 3) + 4]) =
            make_float4(acc[i][4], acc[i][5], acc[i][6], acc[i][7]);
    }
}

// Reduce 64 partials; write TRANSPOSED bf16 so gemm_bf16 consumes it as W[N,K].
__global__ __launch_bounds__(256) void ktv_reduce(
    const float* __restrict__ part, __bf16* __restrict__ ktvT)
{
    const int t = blockIdx.x * 256 + threadIdx.x;   // 0..16383
    const int i = t >> 7;
    const int j = t & 127;
    float s = 0.0f;
    for (int b = 0; b < 64; b++) s += part[(long)b * (DK * DK) + t];
    ktvT[j * DK + i] = (__bf16)s;
}

// ---------------------------------------------------------------------------
extern "C" void kernel_launch(void* const* d_in, const int* in_sizes, int n_in,
                              void* d_out, int out_size, void* d_ws, size_t ws_size,
                              hipStream_t stream) {
    const float* x  = (const float*)d_in[0];
    const float* Wq = (const float*)d_in[1];
    const float* bq = (const float*)d_in[2];
    const float* Wk = (const float*)d_in[3];
    const float* bk = (const float*)d_in[4];
    const float* Wv = (const float*)d_in[5];
    const float* bv = (const float*)d_in[6];
    const float* Wp = (const float*)d_in[7];
    const float* bp = (const float*)d_in[8];
    const float* W1 = (const float*)d_in[9];
    const float* b1 = (const float*)d_in[10];
    const float* W2 = (const float*)d_in[11];
    const float* b2 = (const float*)d_in[12];
    float* out = (float*)d_out;

    char* ws = (char*)d_ws;
    const size_t MB = 1ull << 20;
    __bf16* xb    = (__bf16*)(ws);              // 16.8 MB
    __bf16* x2b   = (__bf16*)(ws +  17 * MB);   // 16.8 MB
    __bf16* Hb    = (__bf16*)(ws +  34 * MB);   // 67.1 MB
    __bf16* QKVb  = (__bf16*)(ws + 102 * MB);   //  6.3 MB  [8192][384]
    __bf16* W1b   = (__bf16*)(ws + 109 * MB);   //  8.4 MB
    __bf16* W2b   = (__bf16*)(ws + 118 * MB);   //  8.4 MB
    __bf16* Wqkvb = (__bf16*)(ws + 127 * MB);   //  0.8 MB  [384][1024]
    __bf16* Wpb   = (__bf16*)(ws + 128 * MB);   //  0.3 MB
    float*  Part  = (float*) (ws + 129 * MB);   //  4.2 MB
    __bf16* KtvTb = (__bf16*)(ws + 134 * MB);   //  32 KB
    __bf16* Ctxb  = (__bf16*)(ws + 135 * MB);   //  2.1 MB
    float*  bqkvf = (float*) (ws + 138 * MB);   //  1.5 KB

    const dim3 blk(256);

    // ---- casts ----
    cast_f32_bf16<<<2048, blk, 0, stream>>>(x,  xb,           MROWS * DMODEL / 8);
    cast_f32_bf16<<<64,   blk, 0, stream>>>(Wq, Wqkvb,        DK * DMODEL / 8);
    cast_f32_bf16<<<64,   blk, 0, stream>>>(Wk, Wqkvb + DK * DMODEL,     DK * DMODEL / 8);
    cast_f32_bf16<<<64,   blk, 0, stream>>>(Wv, Wqkvb + 2 * DK * DMODEL, DK * DMODEL / 8);
    cast_f32_bf16<<<64,   blk, 0, stream>>>(Wp, Wpb,          DMODEL * DK / 8);
    cast_f32_bf16<<<1024, blk, 0, stream>>>(W1, W1b,          DFF * DMODEL / 8);
    cast_f32_bf16<<<1024, blk, 0, stream>>>(W2, W2b,          DMODEL * DFF / 8);
    pack_bias3<<<1, 128, 0, stream>>>(bq, bk, bv, bqkvf);

    // ---- QKV packed projection: [8192,1024]@[384,1024]^T -> bf16 [8192,384]
    gemm_bf16<false,false,true,true><<<dim3(3, 64), blk, 0, stream>>>(
        xb, DMODEL, Wqkvb, bqkvf, nullptr, QKVb, 3 * DK, DMODEL);

    // ---- KtV (128x128), deterministic 2-stage, output transposed bf16
    ktv_partial<<<64, blk, 0, stream>>>(QKVb + DK, QKVb + 2 * DK, 3 * DK, Part);
    ktv_reduce <<<64, blk, 0, stream>>>(Part, KtvTb);

    // ---- context = Q @ KtV -> bf16 [8192,128]
    gemm_bf16<false,false,false,true><<<dim3(1, 64), blk, 0, stream>>>(
        QKVb, 3 * DK, KtvTb, nullptr, nullptr, Ctxb, DK, DK);

    // ---- x2 = x + context @ Wp^T + bp -> fp32 d_out
    gemm_bf16<false,true,true,false><<<dim3(8, 64), blk, 0, stream>>>(
        Ctxb, DK, Wpb, bp, x, out, DMODEL, DK);

    // ---- x2 -> bf16
    cast_f32_bf16<<<2048, blk, 0, stream>>>(out, x2b, MROWS * DMODEL / 8);

    // ---- h = relu(x2 @ W1^T + b1) -> bf16 [8192,4096]
    gemm_bf16<true,false,true,true><<<dim3(32, 64), blk, 0, stream>>>(
        x2b, DMODEL, W1b, b1, nullptr, Hb, DFF, DMODEL);

    // ---- y = x2 + h @ W2^T + b2 -> fp32 d_out (same-thread RMW, safe)
    gemm_bf16<false,true,true,false><<<dim3(8, 64), blk, 0, stream>>>(
        Hb, DFF, W2b, b2, out, out, DMODEL, DFF);
}